// Round 5
// baseline (1704.131 us; speedup 1.0000x reference)
//
#include <hip/hip_runtime.h>
#include <math.h>

#define D_MODEL 768
#define D_INNER 1536
#define D_STATE 16
#define DEPTH   12
#define LSEQ    197
#define BATCH   8
#define NPATCH  196
#define ROWS    (BATCH*LSEQ)    // 1576
#define PROWS   (BATCH*NPATCH)  // 1568
#define MPAD    1664            // 26*64, padded row count for bf16 A operands
#define LP      208             // padded time axis (13*16)
#define NDTX    1664            // dt GEMM N: 1536 dt cols + 16 x_proj(B) cols + 112 pad

typedef __bf16 bf16x8 __attribute__((ext_vector_type(8)));
typedef float  floatx4 __attribute__((ext_vector_type(4)));
typedef __attribute__((address_space(1))) void gvoid;
typedef __attribute__((address_space(3))) void svoid;

__device__ __forceinline__ float siluf(float x) { return x / (1.f + __expf(-x)); }
__device__ __forceinline__ float softplusf(float v) {
  return (v > 20.f) ? v : log1pf(__expf(v));
}

__device__ __forceinline__ void gload_lds16(const void* g, void* s) {
  __builtin_amdgcn_global_load_lds((const gvoid*)g, (svoid*)s, 16, 0, 0);
}

// DPP cross-lane add within 16-lane rows (VALU pipe, no DS).
template<int CTRL>
__device__ __forceinline__ float dpp_addf(float x) {
  union { float f; int i; } a, b;
  a.f = x;
  b.i = __builtin_amdgcn_update_dpp(0, a.i, CTRL, 0xF, 0xF, true);
  return x + b.f;
}

// ---------------- fp32 -> bf16 conversion (vectorized, n % 4 == 0) ----------------
__global__ void cvt_k(const float* __restrict__ src, __bf16* __restrict__ dst, int n) {
  int i = (blockIdx.x * 256 + threadIdx.x) * 4;
  if (i >= n) return;
  float4 v = *(const float4*)(src + i);
  union { __bf16 h[4]; unsigned long long u; } p;
  p.h[0] = (__bf16)v.x; p.h[1] = (__bf16)v.y; p.h[2] = (__bf16)v.z; p.h[3] = (__bf16)v.w;
  *(unsigned long long*)(dst + i) = p.u;
}

// ---- combined dt_proj + x_proj(B rows) weight -> bf16 [DEPTH][NDTX][1536] ----
__global__ void cvt_dtx_k(const float* __restrict__ dtw, const float* __restrict__ xpw,
                          __bf16* __restrict__ dst) {
  size_t i = ((size_t)blockIdx.x * 256 + threadIdx.x) * 4;
  const size_t TOT = (size_t)DEPTH * 1552 * 1536;
  if (i >= TOT) return;
  int layer = (int)(i / (1552 * 1536));
  int rem = (int)(i - (size_t)layer * (1552 * 1536));
  int r = rem / 1536, c = rem - r * 1536;
  const float* src = (r < 1536)
      ? dtw + ((size_t)layer * 1536 + r) * 1536 + c
      : xpw + ((size_t)layer * 32 + 16 + (r - 1536)) * 1536 + c;
  float4 v = *(const float4*)src;
  union { __bf16 h[4]; unsigned long long u; } p;
  p.h[0] = (__bf16)v.x; p.h[1] = (__bf16)v.y; p.h[2] = (__bf16)v.z; p.h[3] = (__bf16)v.w;
  *(unsigned long long*)(dst + ((size_t)layer * NDTX + r) * 1536 + c) = p.u;
}

// ---------------- im2col for patch embed (bf16 out) ----------------
__global__ void im2col_k(const float* __restrict__ x, __bf16* __restrict__ col) {
  int idx = blockIdx.x * 256 + threadIdx.x;
  if (idx >= PROWS * 768) return;
  int row = idx / 768, i = idx % 768;
  int b = row / NPATCH, p = row % NPATCH;
  int py = p / 14, px = p % 14;
  int ci = i >> 8, rem = i & 255;
  int ky = rem >> 4, kx = rem & 15;
  col[idx] = (__bf16)x[(((size_t)b*3 + ci)*224 + (py*16+ky))*224 + (px*16+kx)];
}

// ---- fused assemble (cls + patches + pos) -> t, plus layer-0 LN -> xn_b ----
__global__ void assemble_ln_k(const float* __restrict__ P, const float* __restrict__ cb,
                              const float* __restrict__ cls, const float* __restrict__ pos,
                              const float* __restrict__ w, const float* __restrict__ bb,
                              float* __restrict__ t, __bf16* __restrict__ o) {
  int bl = blockIdx.x; int b = bl / LSEQ, l = bl % LSEQ;
  float v[3]; float s = 0.f, ss = 0.f;
  #pragma unroll
  for (int i = 0; i < 3; i++) {
    int c = threadIdx.x + i*256;
    float x;
    if (l == 0) x = cls[c];
    else        x = P[((size_t)b*NPATCH + (l-1))*768 + c] + cb[c];
    x += pos[(size_t)l*768 + c];
    t[(size_t)bl*768 + c] = x;
    v[i] = x; s += x; ss += x*x;
  }
  __shared__ float red[8];
  #pragma unroll
  for (int off = 32; off; off >>= 1) {
    s  += __shfl_down(s, off, 64);
    ss += __shfl_down(ss, off, 64);
  }
  int wv = threadIdx.x >> 6;
  if ((threadIdx.x & 63) == 0) { red[wv] = s; red[wv+4] = ss; }
  __syncthreads();
  if (threadIdx.x == 0) {
    float S = red[0]+red[1]+red[2]+red[3];
    float SS = red[4]+red[5]+red[6]+red[7];
    float m = S * (1.f/768.f);
    float var = SS * (1.f/768.f) - m*m;
    red[0] = m; red[1] = rsqrtf(var + 1e-5f);
  }
  __syncthreads();
  float m = red[0], r = red[1];
  #pragma unroll
  for (int i = 0; i < 3; i++) {
    int c = threadIdx.x + i*256;
    o[(size_t)bl*768 + c] = (__bf16)((v[i]-m)*r*w[c] + bb[c]);
  }
}

// ---------------- plain layernorm of t (residual master) -> o ----------------
template<typename T>
__global__ void ln_k(const float* __restrict__ t, const float* __restrict__ w,
                     const float* __restrict__ b, T* __restrict__ o) {
  int row = blockIdx.x;
  const float* tr = t + (size_t)row * 768;
  float v[3]; float s = 0.f, ss = 0.f;
  #pragma unroll
  for (int i = 0; i < 3; i++) {
    int c = threadIdx.x + i*256;
    float x = tr[c];
    v[i] = x; s += x; ss += x*x;
  }
  __shared__ float red[8];
  #pragma unroll
  for (int off = 32; off; off >>= 1) {
    s  += __shfl_down(s, off, 64);
    ss += __shfl_down(ss, off, 64);
  }
  int wv = threadIdx.x >> 6;
  if ((threadIdx.x & 63) == 0) { red[wv] = s; red[wv+4] = ss; }
  __syncthreads();
  if (threadIdx.x == 0) {
    float S = red[0]+red[1]+red[2]+red[3];
    float SS = red[4]+red[5]+red[6]+red[7];
    float m = S * (1.f/768.f);
    float var = SS * (1.f/768.f) - m*m;
    red[0] = m; red[1] = rsqrtf(var + 1e-5f);
  }
  __syncthreads();
  float m = red[0], r = red[1];
  #pragma unroll
  for (int i = 0; i < 3; i++) {
    int c = threadIdx.x + i*256;
    o[(size_t)row*768 + c] = (T)((v[i]-m)*r*w[c] + b[c]);
  }
}

// ---------------- bf16 MFMA GEMM v3: TM=64, TN=128, BK=64, XCD swizzle ------
// mmajor=0: combo-major XCD chunks (each XCD: full A + its B slices) — best
// when B is the big operand (in_proj, dt). mmajor=1: m-major chunks (each
// XCD: its A slice + full B) — best when A >> B (out_proj).
// atomicC=1: epilogue atomically accumulates into C (residual t) instead of
// storing split-K partials — all z-splits add into the same buffer.
__global__ __launch_bounds__(256) void mgemm3_k(const __bf16* __restrict__ A,
    const __bf16* __restrict__ W, float* __restrict__ C, size_t pstride,
    int M, int N, int K, int Ksub, int combos, int nt, int mmajor, int atomicC) {
  __shared__ __bf16 sA[2][64*64];
  __shared__ __bf16 sB[2][128*64];
  const int lin = blockIdx.x;
  const int nwg = combos * 25;
  const int q = nwg >> 3, r = nwg & 7;
  const int xcd = lin & 7, idx = lin >> 3;
  const int v = (xcd < r ? xcd * (q + 1) : r * (q + 1) + (xcd - r) * q) + idx;
  int c, mt;
  if (mmajor) { mt = v / combos; c = v - mt * combos; }
  else        { c = v / 25;      mt = v - c * 25; }
  const int ntile = c % nt, z = c / nt;
  const int m0 = mt * 64, n0 = ntile * 128;
  const int kbeg = z * Ksub, kend = kbeg + Ksub;

  const int tid = threadIdx.x, wave = tid >> 6, lane = tid & 63;
  const int wm = (wave & 1) * 32, wn = (wave >> 1) * 64;

  floatx4 acc[2][4] = {};

  const int srow = tid >> 3;
  const int scol = ((tid & 7) ^ (srow & 7)) * 8;
  const __bf16* gA = A + (size_t)(m0 + srow) * K + scol;
  const __bf16* gB = W + (size_t)(n0 + srow) * K + scol;

  const int lm = lane & 15, lk = lane >> 4;
  const int g0 = ((lk    ) ^ (lane & 7)) * 8;
  const int g1 = ((lk + 4) ^ (lane & 7)) * 8;

  int buf = 0;
  {
    #pragma unroll
    for (int p = 0; p < 2; p++)
      gload_lds16(gA + (size_t)(p*32)*K + kbeg, sA[0] + p*2048 + tid*8);
    #pragma unroll
    for (int p = 0; p < 4; p++)
      gload_lds16(gB + (size_t)(p*32)*K + kbeg, sB[0] + p*2048 + tid*8);
  }

  for (int k0 = kbeg; k0 < kend; k0 += 64) {
    __syncthreads();
    if (k0 + 64 < kend) {
      const int nb = buf ^ 1;
      #pragma unroll
      for (int p = 0; p < 2; p++)
        gload_lds16(gA + (size_t)(p*32)*K + (k0+64), sA[nb] + p*2048 + tid*8);
      #pragma unroll
      for (int p = 0; p < 4; p++)
        gload_lds16(gB + (size_t)(p*32)*K + (k0+64), sB[nb] + p*2048 + tid*8);
    }
    const __bf16* pA = sA[buf] + (wm + lm) * 64;
    const __bf16* pB = sB[buf] + (wn + lm) * 64;
    bf16x8 a0[2], a1[2], b0[4], b1[4];
    #pragma unroll
    for (int i = 0; i < 2; i++) {
      a0[i] = *(const bf16x8*)(pA + i*1024 + g0);
      a1[i] = *(const bf16x8*)(pA + i*1024 + g1);
    }
    #pragma unroll
    for (int j = 0; j < 4; j++) {
      b0[j] = *(const bf16x8*)(pB + j*1024 + g0);
      b1[j] = *(const bf16x8*)(pB + j*1024 + g1);
    }
    #pragma unroll
    for (int i = 0; i < 2; i++)
      #pragma unroll
      for (int j = 0; j < 4; j++) {
        acc[i][j] = __builtin_amdgcn_mfma_f32_16x16x32_bf16(a0[i], b0[j], acc[i][j], 0, 0, 0);
        acc[i][j] = __builtin_amdgcn_mfma_f32_16x16x32_bf16(a1[i], b1[j], acc[i][j], 0, 0, 0);
      }
    buf ^= 1;
  }

  float* Cp = C + (size_t)z * pstride;
  const int en = n0 + wn + lm;
  const int em = m0 + wm + lk * 4;
  if (atomicC) {
    #pragma unroll
    for (int i = 0; i < 2; i++) {
      #pragma unroll
      for (int r2 = 0; r2 < 4; r2++) {
        int m = em + i * 16 + r2;
        if (m >= M) continue;
        #pragma unroll
        for (int j = 0; j < 4; j++)
          atomicAdd(&C[(size_t)m * N + en + j * 16], acc[i][j][r2]);
      }
    }
  } else {
    #pragma unroll
    for (int i = 0; i < 2; i++) {
      #pragma unroll
      for (int r2 = 0; r2 < 4; r2++) {
        int m = em + i * 16 + r2;
        if (m >= M) continue;
        #pragma unroll
        for (int j = 0; j < 4; j++)
          Cp[(size_t)m * N + en + j * 16] = acc[i][j][r2];
      }
    }
  }
}

// ---------------- depthwise conv1d + silu -> bf16 GEMM-A operand only -----------
__global__ __launch_bounds__(256) void convf_k(const float* __restrict__ xz,
    const float* __restrict__ cw, const float* __restrict__ cb,
    __bf16* __restrict__ xc_b) {
  const int b = blockIdx.x, dc = blockIdx.y, lc = blockIdx.z * 28;
  const int d = dc * 256 + threadIdx.x;
  const int lend = min(lc + 28, LSEQ);
  const float* w = cw + (size_t)d * 4;
  const float w0 = w[0], w1 = w[1], w2 = w[2], w3 = w[3];
  const float bias = cb[d];
  float xm3 = 0.f, xm2 = 0.f, xm1 = 0.f;
  const size_t rowbase = ((size_t)b * LSEQ) * 3072 + d;
  if (lc >= 3) {
    xm3 = xz[rowbase + (size_t)(lc-3)*3072];
    xm2 = xz[rowbase + (size_t)(lc-2)*3072];
    xm1 = xz[rowbase + (size_t)(lc-1)*3072];
  }
  for (int l = lc; l < lend; l++) {
    float x0 = xz[rowbase + (size_t)l*3072];
    float cv = w0*xm3 + w1*xm2 + w2*xm1 + w3*x0 + bias;
    xm3 = xm2; xm2 = xm1; xm1 = x0;
    xc_b[((size_t)b*LSEQ + l)*D_INNER + d] = (__bf16)siluf(cv);
  }
}

// ---------------- fused reduce+transpose+conv+gates+selective scan ----------------
__global__ __launch_bounds__(256) void scan4_k(const float* __restrict__ p0,
    const float* __restrict__ xz, const float* __restrict__ dt_bias,
    const float* __restrict__ cw, const float* __restrict__ cb,
    const float* __restrict__ A_log, const float* __restrict__ Dp,
    __bf16* __restrict__ y) {
  __shared__ __align__(16) float sx[19*16];   // x tile + 3 halo rows, [li][dl]
  __shared__ __align__(16) float sdv[16*20];  // softplus(dt) [dl][l], pad 20
  __shared__ __align__(16) float sbn[16*20];  // B [n][l]
  __shared__ __align__(16) float sxc[16*20];  // silu(conv(x)) [dl][l]
  __shared__ __align__(16) float sgm[16*20];  // silu(z) [dl][l]

  const float* p1 = p0 + (size_t)ROWS * NDTX;
  const int t = threadIdx.x;
  const int b = blockIdx.x / 96;           // 96 blocks per batch (1536/16)
  const int d0 = (blockIdx.x - b * 96) * 16;
  const int lrow = t >> 4, dl = t & 15;    // staging role
  const int grp = t >> 4, n = t & 15;      // compute role (same decomposition)

  const float* wp = cw + (size_t)(d0 + dl) * 4;
  const float w0 = wp[0], w1 = wp[1], w2 = wp[2], w3 = wp[3];
  const float cbias  = cb[d0 + dl];
  const float spbias = dt_bias[d0 + dl];
  const float a  = -__expf(A_log[(size_t)(d0 + grp) * 16 + n]);
  const float dp = Dp[d0 + grp];

  const size_t browf = (size_t)b * LSEQ;
  float s = 0.f;

  for (int l0 = 0; l0 < LP; l0 += 16) {
    // ---- phase 1: global loads ----
    int gl = l0 + lrow;
    float pdv = 0.f, pbn = 0.f, zv = 0.f, xval = 0.f;
    if (gl < LSEQ) {
      size_t row = browf + gl;
      size_t pr = row * NDTX;
      pdv = p0[pr + d0 + dl] + p1[pr + d0 + dl] + spbias;
      pbn = p0[pr + 1536 + dl] + p1[pr + 1536 + dl];
      size_t xr = row * 3072;
      zv   = xz[xr + 1536 + d0 + dl];
      xval = xz[xr + d0 + dl];
    }
    sx[(lrow + 3) * 16 + dl] = xval;
    if (t < 48) {  // 3 halo rows l0-3..l0-1 (always < LSEQ)
      int hl = t >> 4, hdl = t & 15;
      int gh = l0 - 3 + hl;
      float hv = 0.f;
      if (gh >= 0) hv = xz[(browf + gh) * 3072 + d0 + hdl];
      sx[hl * 16 + hdl] = hv;
    }
    __syncthreads();
    // ---- phase 2: derived tiles ----
    float xc = w0 * sx[lrow*16 + dl] + w1 * sx[(lrow+1)*16 + dl]
             + w2 * sx[(lrow+2)*16 + dl] + w3 * sx[(lrow+3)*16 + dl] + cbias;
    sxc[dl*20 + lrow] = siluf(xc);
    sdv[dl*20 + lrow] = (gl < LSEQ) ? softplusf(pdv) : 0.f;
    sbn[dl*20 + lrow] = pbn;
    sgm[dl*20 + lrow] = siluf(zv);
    __syncthreads();
    // ---- phase 3: scan (per lane: channel d0+grp, state n) ----
    float dv[16], xv[16], bn[16];
    #pragma unroll
    for (int q = 0; q < 4; q++) {
      *(floatx4*)(dv + q*4) = *(const floatx4*)(sdv + grp*20 + q*4);
      *(floatx4*)(xv + q*4) = *(const floatx4*)(sxc + grp*20 + q*4);
      *(floatx4*)(bn + q*4) = *(const floatx4*)(sbn + n*20   + q*4);
    }
    float gm = sgm[grp*20 + n];
    float yreg = 0.f, xvn = 0.f;
    #pragma unroll
    for (int j = 0; j < 16; j++) {
      s = __expf(dv[j] * a) * s + (dv[j] * xv[j]) * bn[j];
      float part = s * bn[j];
      part = dpp_addf<0xB1>(part);    // xor 1
      part = dpp_addf<0x4E>(part);    // xor 2
      part = dpp_addf<0x141>(part);   // xor 7 (row_half_mirror)
      part = dpp_addf<0x140>(part);   // xor 15 (row_mirror)
      yreg = (n == j) ? part : yreg;
      xvn  = (n == j) ? xv[j] : xvn;
    }
    int lo = l0 + n;
    if (lo < LSEQ)
      y[(browf + lo) * D_INNER + d0 + grp] = (__bf16)((yreg + dp * xvn) * gm);
    __syncthreads();  // protect LDS reuse by next chunk's phase 2
  }
}

extern "C" void kernel_launch(void* const* d_in, const int* in_sizes, int n_in,
                              void* d_out, int out_size, void* d_ws, size_t ws_size,
                              hipStream_t stream) {
  const float* x         = (const float*)d_in[0];
  const float* conv_w    = (const float*)d_in[1];
  const float* conv_b    = (const float*)d_in[2];
  const float* cls_token = (const float*)d_in[3];
  const float* pos_embed = (const float*)d_in[4];
  const float* ln_w      = (const float*)d_in[5];
  const float* ln_b      = (const float*)d_in[6];
  const float* in_proj_w = (const float*)d_in[7];
  const float* conv1d_w  = (const float*)d_in[8];
  const float* conv1d_b  = (const float*)d_in[9];
  const float* x_proj_w  = (const float*)d_in[10];
  const float* dt_proj_w = (const float*)d_in[11];
  const float* dt_proj_b = (const float*)d_in[12];
  const float* A_log     = (const float*)d_in[13];
  const float* D_param   = (const float*)d_in[14];
  const float* out_proj_w= (const float*)d_in[15];
  const float* norm_w    = (const float*)d_in[16];
  const float* norm_b    = (const float*)d_in[17];

  const int N_IN  = 2*D_INNER*D_MODEL;   // 2359296
  const int N_OUT = D_MODEL*D_INNER;     // 1179648

  char* wsb = (char*)d_ws;
  size_t off = 0;
  float* t     = (float*)(wsb + off); off += (size_t)ROWS*768*4;
  float* xz    = (float*)(wsb + off); off += (size_t)ROWS*3072*4;
  float* part  = (float*)(wsb + off); off += (size_t)2*ROWS*NDTX*4;  // dt split-K partials
  __bf16* xn_b = (__bf16*)(wsb + off); off += (size_t)MPAD*768*2;
  __bf16* xc_b = (__bf16*)(wsb + off); off += (size_t)MPAD*1536*2;
  __bf16* y_b  = (__bf16*)(wsb + off); off += (size_t)MPAD*1536*2;
  __bf16* col_b= (__bf16*)(wsb + off); off += (size_t)MPAD*768*2;
  __bf16* cw_b = (__bf16*)(wsb + off); off += (size_t)768*768*2;
  __bf16* wb_in  = (__bf16*)(wsb + off); off += (size_t)DEPTH*N_IN*2;
  __bf16* wb_dtx = (__bf16*)(wsb + off); off += (size_t)DEPTH*NDTX*1536*2;
  __bf16* wb_out = (__bf16*)(wsb + off); off += (size_t)DEPTH*N_OUT*2;

  // ---- upfront: all weight conversions ----
  cvt_k<<<(768*768/4 + 255)/256, 256, 0, stream>>>(conv_w, cw_b, 768*768);
  cvt_k<<<(DEPTH*N_IN/4 + 255)/256, 256, 0, stream>>>(in_proj_w, wb_in, DEPTH*N_IN);
  cvt_dtx_k<<<(DEPTH*1552*1536/4 + 255)/256, 256, 0, stream>>>(dt_proj_w, x_proj_w, wb_dtx);
  cvt_k<<<(DEPTH*N_OUT/4 + 255)/256, 256, 0, stream>>>(out_proj_w, wb_out, DEPTH*N_OUT);

  // ---- patch embed as bf16 MFMA GEMM ----
  float* P = xz;  // reuse
  im2col_k<<<(PROWS*768 + 255)/256, 256, 0, stream>>>(x, col_b);
  mgemm3_k<<<25*6, 256, 0, stream>>>(col_b, cw_b, P, 0, PROWS, 768, 768, 768, 6, 6, 0, 0);
  // fused assemble + layer-0 LN
  assemble_ln_k<<<ROWS, 256, 0, stream>>>(P, conv_b, cls_token, pos_embed,
                                          ln_w, ln_b, t, xn_b);

  for (int i = 0; i < DEPTH; i++) {
    // in_proj: N=3072 (nt=24), no split-K -> combos 24, combo-major
    mgemm3_k<<<25*24, 256, 0, stream>>>(xn_b, wb_in + (size_t)i*N_IN, xz, 0,
                                        ROWS, 3072, 768, 768, 24, 24, 0, 0);
    convf_k<<<dim3(8, 6, 8), 256, 0, stream>>>(xz, conv1d_w + (size_t)i*D_INNER*4,
        conv1d_b + (size_t)i*D_INNER, xc_b);
    // dt_proj + folded x_proj(B): N=NDTX (nt=13), split-K x2 -> combos 26, combo-major
    mgemm3_k<<<25*26, 256, 0, stream>>>(xc_b, wb_dtx + (size_t)i*NDTX*1536, part,
        (size_t)ROWS*NDTX, ROWS, NDTX, 1536, 768, 26, 13, 0, 0);
    // fused reduce+transpose+conv+gates+scan
    scan4_k<<<(BATCH*D_INNER)/16, 256, 0, stream>>>(part, xz,
        dt_proj_b + (size_t)i*D_INNER, conv1d_w + (size_t)i*D_INNER*4,
        conv1d_b + (size_t)i*D_INNER, A_log + (size_t)i*D_INNER*D_STATE,
        D_param + (size_t)i*D_INNER, y_b);
    // out_proj: N=768 (nt=6), split-K x4 -> combos 24; m-major XCD chunks
    // (A=y_b 4.8MB >> B 2.4MB); epilogue atomically accumulates into t.
    mgemm3_k<<<25*24, 256, 0, stream>>>(y_b, wb_out + (size_t)i*N_OUT, t,
        0, ROWS, 768, 1536, 384, 24, 6, 1, 1);
    // LN of updated residual -> next layer's bf16 input (or final fp32 out)
    if (i < DEPTH-1)
      ln_k<__bf16><<<ROWS, 256, 0, stream>>>(t,
          ln_w + (size_t)(i+1)*768, ln_b + (size_t)(i+1)*768, xn_b);
    else
      ln_k<float><<<ROWS, 256, 0, stream>>>(t, norm_w, norm_b, (float*)d_out);
  }
}

// Round 6
// 1620.835 us; speedup vs baseline: 1.0514x; 1.0514x over previous
//
#include <hip/hip_runtime.h>
#include <math.h>

#define D_MODEL 768
#define D_INNER 1536
#define D_STATE 16
#define DEPTH   12
#define LSEQ    197
#define BATCH   8
#define NPATCH  196
#define ROWS    (BATCH*LSEQ)    // 1576
#define PROWS   (BATCH*NPATCH)  // 1568
#define MPAD    1664            // 26*64, padded row count for bf16 A operands
#define LP      208             // padded time axis (13*16)
#define NDTX    1664            // dt GEMM N: 1536 dt cols + 16 x_proj(B) cols + 112 pad

typedef __bf16 bf16x8 __attribute__((ext_vector_type(8)));
typedef float  floatx4 __attribute__((ext_vector_type(4)));
typedef __attribute__((address_space(1))) void gvoid;
typedef __attribute__((address_space(3))) void svoid;

__device__ __forceinline__ float siluf(float x) { return x / (1.f + __expf(-x)); }
__device__ __forceinline__ float softplusf(float v) {
  return (v > 20.f) ? v : log1pf(__expf(v));
}

__device__ __forceinline__ void gload_lds16(const void* g, void* s) {
  __builtin_amdgcn_global_load_lds((const gvoid*)g, (svoid*)s, 16, 0, 0);
}

// DPP cross-lane add within 16-lane rows (VALU pipe, no DS).
template<int CTRL>
__device__ __forceinline__ float dpp_addf(float x) {
  union { float f; int i; } a, b;
  a.f = x;
  b.i = __builtin_amdgcn_update_dpp(0, a.i, CTRL, 0xF, 0xF, true);
  return x + b.f;
}

// ---------------- fp32 -> bf16 conversion (vectorized, n % 4 == 0) ----------------
__global__ void cvt_k(const float* __restrict__ src, __bf16* __restrict__ dst, int n) {
  int i = (blockIdx.x * 256 + threadIdx.x) * 4;
  if (i >= n) return;
  float4 v = *(const float4*)(src + i);
  union { __bf16 h[4]; unsigned long long u; } p;
  p.h[0] = (__bf16)v.x; p.h[1] = (__bf16)v.y; p.h[2] = (__bf16)v.z; p.h[3] = (__bf16)v.w;
  *(unsigned long long*)(dst + i) = p.u;
}

// ---- combined dt_proj + x_proj(B rows) weight -> bf16 [DEPTH][NDTX][1536] ----
__global__ void cvt_dtx_k(const float* __restrict__ dtw, const float* __restrict__ xpw,
                          __bf16* __restrict__ dst) {
  size_t i = ((size_t)blockIdx.x * 256 + threadIdx.x) * 4;
  const size_t TOT = (size_t)DEPTH * 1552 * 1536;
  if (i >= TOT) return;
  int layer = (int)(i / (1552 * 1536));
  int rem = (int)(i - (size_t)layer * (1552 * 1536));
  int r = rem / 1536, c = rem - r * 1536;
  const float* src = (r < 1536)
      ? dtw + ((size_t)layer * 1536 + r) * 1536 + c
      : xpw + ((size_t)layer * 32 + 16 + (r - 1536)) * 1536 + c;
  float4 v = *(const float4*)src;
  union { __bf16 h[4]; unsigned long long u; } p;
  p.h[0] = (__bf16)v.x; p.h[1] = (__bf16)v.y; p.h[2] = (__bf16)v.z; p.h[3] = (__bf16)v.w;
  *(unsigned long long*)(dst + ((size_t)layer * NDTX + r) * 1536 + c) = p.u;
}

// ---------------- im2col for patch embed (bf16 out) ----------------
__global__ void im2col_k(const float* __restrict__ x, __bf16* __restrict__ col) {
  int idx = blockIdx.x * 256 + threadIdx.x;
  if (idx >= PROWS * 768) return;
  int row = idx / 768, i = idx % 768;
  int b = row / NPATCH, p = row % NPATCH;
  int py = p / 14, px = p % 14;
  int ci = i >> 8, rem = i & 255;
  int ky = rem >> 4, kx = rem & 15;
  col[idx] = (__bf16)x[(((size_t)b*3 + ci)*224 + (py*16+ky))*224 + (px*16+kx)];
}

// ---- fused assemble (cls + patches + pos) -> t, plus layer-0 LN -> xn_b ----
__global__ void assemble_ln_k(const float* __restrict__ P, const float* __restrict__ cb,
                              const float* __restrict__ cls, const float* __restrict__ pos,
                              const float* __restrict__ w, const float* __restrict__ bb,
                              float* __restrict__ t, __bf16* __restrict__ o) {
  int bl = blockIdx.x; int b = bl / LSEQ, l = bl % LSEQ;
  float v[3]; float s = 0.f, ss = 0.f;
  #pragma unroll
  for (int i = 0; i < 3; i++) {
    int c = threadIdx.x + i*256;
    float x;
    if (l == 0) x = cls[c];
    else        x = P[((size_t)b*NPATCH + (l-1))*768 + c] + cb[c];
    x += pos[(size_t)l*768 + c];
    t[(size_t)bl*768 + c] = x;
    v[i] = x; s += x; ss += x*x;
  }
  __shared__ float red[8];
  #pragma unroll
  for (int off = 32; off; off >>= 1) {
    s  += __shfl_down(s, off, 64);
    ss += __shfl_down(ss, off, 64);
  }
  int wv = threadIdx.x >> 6;
  if ((threadIdx.x & 63) == 0) { red[wv] = s; red[wv+4] = ss; }
  __syncthreads();
  if (threadIdx.x == 0) {
    float S = red[0]+red[1]+red[2]+red[3];
    float SS = red[4]+red[5]+red[6]+red[7];
    float m = S * (1.f/768.f);
    float var = SS * (1.f/768.f) - m*m;
    red[0] = m; red[1] = rsqrtf(var + 1e-5f);
  }
  __syncthreads();
  float m = red[0], r = red[1];
  #pragma unroll
  for (int i = 0; i < 3; i++) {
    int c = threadIdx.x + i*256;
    o[(size_t)bl*768 + c] = (__bf16)((v[i]-m)*r*w[c] + bb[c]);
  }
}

// ---------------- layernorm over 768 with optional fused split-K residual ----
// FUSE: 0 = plain LN(t); 1 = t += sum(4 partials), store t, LN; 2 = same but
// don't store t (final layer).
template<typename T, int FUSE>
__global__ void lnf_k(float* __restrict__ t, const float* __restrict__ part,
                      const float* __restrict__ w, const float* __restrict__ b,
                      T* __restrict__ o) {
  int row = blockIdx.x;
  float* tr = t + (size_t)row * 768;
  float v[3]; float s = 0.f, ss = 0.f;
  #pragma unroll
  for (int i = 0; i < 3; i++) {
    int c = threadIdx.x + i*256;
    float x = tr[c];
    if (FUSE) {
      const size_t S = (size_t)ROWS*768, idx = (size_t)row*768 + c;
      x += part[idx] + part[S+idx] + part[2*S+idx] + part[3*S+idx];
      if (FUSE == 1) tr[c] = x;
    }
    v[i] = x; s += x; ss += x*x;
  }
  __shared__ float red[8];
  #pragma unroll
  for (int off = 32; off; off >>= 1) {
    s  += __shfl_down(s, off, 64);
    ss += __shfl_down(ss, off, 64);
  }
  int wv = threadIdx.x >> 6;
  if ((threadIdx.x & 63) == 0) { red[wv] = s; red[wv+4] = ss; }
  __syncthreads();
  if (threadIdx.x == 0) {
    float S = red[0]+red[1]+red[2]+red[3];
    float SS = red[4]+red[5]+red[6]+red[7];
    float m = S * (1.f/768.f);
    float var = SS * (1.f/768.f) - m*m;
    red[0] = m; red[1] = rsqrtf(var + 1e-5f);
  }
  __syncthreads();
  float m = red[0], r = red[1];
  #pragma unroll
  for (int i = 0; i < 3; i++) {
    int c = threadIdx.x + i*256;
    o[(size_t)row*768 + c] = (T)((v[i]-m)*r*w[c] + b[c]);
  }
}

// ---------------- bf16 MFMA GEMM v3: TM=64, TN=128, BK=64, XCD swizzle ------
// mmajor=0: combo-major XCD chunks (each XCD: full A + its B slices) — best
// when B is the big operand (in_proj, dt). mmajor=1: m-major chunks (each
// XCD: its A slice + full B) — best when A >> B (out_proj). Plain split-K
// partial stores only (atomic accumulate was a measured disaster: concurrent
// z-split writers contend on the same cachelines -> epilogue serialization).
__global__ __launch_bounds__(256) void mgemm3_k(const __bf16* __restrict__ A,
    const __bf16* __restrict__ W, float* __restrict__ C, size_t pstride,
    int M, int N, int K, int Ksub, int combos, int nt, int mmajor) {
  __shared__ __bf16 sA[2][64*64];
  __shared__ __bf16 sB[2][128*64];
  const int lin = blockIdx.x;
  const int nwg = combos * 25;
  const int q = nwg >> 3, r = nwg & 7;
  const int xcd = lin & 7, idx = lin >> 3;
  const int v = (xcd < r ? xcd * (q + 1) : r * (q + 1) + (xcd - r) * q) + idx;
  int c, mt;
  if (mmajor) { mt = v / combos; c = v - mt * combos; }
  else        { c = v / 25;      mt = v - c * 25; }
  const int ntile = c % nt, z = c / nt;
  const int m0 = mt * 64, n0 = ntile * 128;
  const int kbeg = z * Ksub, kend = kbeg + Ksub;

  const int tid = threadIdx.x, wave = tid >> 6, lane = tid & 63;
  const int wm = (wave & 1) * 32, wn = (wave >> 1) * 64;

  floatx4 acc[2][4] = {};

  const int srow = tid >> 3;
  const int scol = ((tid & 7) ^ (srow & 7)) * 8;
  const __bf16* gA = A + (size_t)(m0 + srow) * K + scol;
  const __bf16* gB = W + (size_t)(n0 + srow) * K + scol;

  const int lm = lane & 15, lk = lane >> 4;
  const int g0 = ((lk    ) ^ (lane & 7)) * 8;
  const int g1 = ((lk + 4) ^ (lane & 7)) * 8;

  int buf = 0;
  {
    #pragma unroll
    for (int p = 0; p < 2; p++)
      gload_lds16(gA + (size_t)(p*32)*K + kbeg, sA[0] + p*2048 + tid*8);
    #pragma unroll
    for (int p = 0; p < 4; p++)
      gload_lds16(gB + (size_t)(p*32)*K + kbeg, sB[0] + p*2048 + tid*8);
  }

  for (int k0 = kbeg; k0 < kend; k0 += 64) {
    __syncthreads();
    if (k0 + 64 < kend) {
      const int nb = buf ^ 1;
      #pragma unroll
      for (int p = 0; p < 2; p++)
        gload_lds16(gA + (size_t)(p*32)*K + (k0+64), sA[nb] + p*2048 + tid*8);
      #pragma unroll
      for (int p = 0; p < 4; p++)
        gload_lds16(gB + (size_t)(p*32)*K + (k0+64), sB[nb] + p*2048 + tid*8);
    }
    const __bf16* pA = sA[buf] + (wm + lm) * 64;
    const __bf16* pB = sB[buf] + (wn + lm) * 64;
    bf16x8 a0[2], a1[2], b0[4], b1[4];
    #pragma unroll
    for (int i = 0; i < 2; i++) {
      a0[i] = *(const bf16x8*)(pA + i*1024 + g0);
      a1[i] = *(const bf16x8*)(pA + i*1024 + g1);
    }
    #pragma unroll
    for (int j = 0; j < 4; j++) {
      b0[j] = *(const bf16x8*)(pB + j*1024 + g0);
      b1[j] = *(const bf16x8*)(pB + j*1024 + g1);
    }
    #pragma unroll
    for (int i = 0; i < 2; i++)
      #pragma unroll
      for (int j = 0; j < 4; j++) {
        acc[i][j] = __builtin_amdgcn_mfma_f32_16x16x32_bf16(a0[i], b0[j], acc[i][j], 0, 0, 0);
        acc[i][j] = __builtin_amdgcn_mfma_f32_16x16x32_bf16(a1[i], b1[j], acc[i][j], 0, 0, 0);
      }
    buf ^= 1;
  }

  float* Cp = C + (size_t)z * pstride;
  const int en = n0 + wn + lm;
  const int em = m0 + wm + lk * 4;
  #pragma unroll
  for (int i = 0; i < 2; i++) {
    #pragma unroll
    for (int r2 = 0; r2 < 4; r2++) {
      int m = em + i * 16 + r2;
      if (m >= M) continue;
      #pragma unroll
      for (int j = 0; j < 4; j++)
        Cp[(size_t)m * N + en + j * 16] = acc[i][j][r2];
    }
  }
}

// ---------------- depthwise conv1d + silu -> bf16 GEMM-A operand only -----------
__global__ __launch_bounds__(256) void convf_k(const float* __restrict__ xz,
    const float* __restrict__ cw, const float* __restrict__ cb,
    __bf16* __restrict__ xc_b) {
  const int b = blockIdx.x, dc = blockIdx.y, lc = blockIdx.z * 28;
  const int d = dc * 256 + threadIdx.x;
  const int lend = min(lc + 28, LSEQ);
  const float* w = cw + (size_t)d * 4;
  const float w0 = w[0], w1 = w[1], w2 = w[2], w3 = w[3];
  const float bias = cb[d];
  float xm3 = 0.f, xm2 = 0.f, xm1 = 0.f;
  const size_t rowbase = ((size_t)b * LSEQ) * 3072 + d;
  if (lc >= 3) {
    xm3 = xz[rowbase + (size_t)(lc-3)*3072];
    xm2 = xz[rowbase + (size_t)(lc-2)*3072];
    xm1 = xz[rowbase + (size_t)(lc-1)*3072];
  }
  for (int l = lc; l < lend; l++) {
    float x0 = xz[rowbase + (size_t)l*3072];
    float cv = w0*xm3 + w1*xm2 + w2*xm1 + w3*x0 + bias;
    xm3 = xm2; xm2 = xm1; xm1 = x0;
    xc_b[((size_t)b*LSEQ + l)*D_INNER + d] = (__bf16)siluf(cv);
  }
}

// ---------------- fused reduce+transpose+conv+gates+selective scan ----------------
__global__ __launch_bounds__(256) void scan4_k(const float* __restrict__ p0,
    const float* __restrict__ xz, const float* __restrict__ dt_bias,
    const float* __restrict__ cw, const float* __restrict__ cb,
    const float* __restrict__ A_log, const float* __restrict__ Dp,
    __bf16* __restrict__ y) {
  __shared__ __align__(16) float sx[19*16];   // x tile + 3 halo rows, [li][dl]
  __shared__ __align__(16) float sdv[16*20];  // softplus(dt) [dl][l], pad 20
  __shared__ __align__(16) float sbn[16*20];  // B [n][l]
  __shared__ __align__(16) float sxc[16*20];  // silu(conv(x)) [dl][l]
  __shared__ __align__(16) float sgm[16*20];  // silu(z) [dl][l]

  const float* p1 = p0 + (size_t)ROWS * NDTX;
  const int t = threadIdx.x;
  const int b = blockIdx.x / 96;           // 96 blocks per batch (1536/16)
  const int d0 = (blockIdx.x - b * 96) * 16;
  const int lrow = t >> 4, dl = t & 15;    // staging role
  const int grp = t >> 4, n = t & 15;      // compute role (same decomposition)

  const float* wp = cw + (size_t)(d0 + dl) * 4;
  const float w0 = wp[0], w1 = wp[1], w2 = wp[2], w3 = wp[3];
  const float cbias  = cb[d0 + dl];
  const float spbias = dt_bias[d0 + dl];
  const float a  = -__expf(A_log[(size_t)(d0 + grp) * 16 + n]);
  const float dp = Dp[d0 + grp];

  const size_t browf = (size_t)b * LSEQ;
  float s = 0.f;

  for (int l0 = 0; l0 < LP; l0 += 16) {
    // ---- phase 1: global loads ----
    int gl = l0 + lrow;
    float pdv = 0.f, pbn = 0.f, zv = 0.f, xval = 0.f;
    if (gl < LSEQ) {
      size_t row = browf + gl;
      size_t pr = row * NDTX;
      pdv = p0[pr + d0 + dl] + p1[pr + d0 + dl] + spbias;
      pbn = p0[pr + 1536 + dl] + p1[pr + 1536 + dl];
      size_t xr = row * 3072;
      zv   = xz[xr + 1536 + d0 + dl];
      xval = xz[xr + d0 + dl];
    }
    sx[(lrow + 3) * 16 + dl] = xval;
    if (t < 48) {  // 3 halo rows l0-3..l0-1 (always < LSEQ)
      int hl = t >> 4, hdl = t & 15;
      int gh = l0 - 3 + hl;
      float hv = 0.f;
      if (gh >= 0) hv = xz[(browf + gh) * 3072 + d0 + hdl];
      sx[hl * 16 + hdl] = hv;
    }
    __syncthreads();
    // ---- phase 2: derived tiles ----
    float xc = w0 * sx[lrow*16 + dl] + w1 * sx[(lrow+1)*16 + dl]
             + w2 * sx[(lrow+2)*16 + dl] + w3 * sx[(lrow+3)*16 + dl] + cbias;
    sxc[dl*20 + lrow] = siluf(xc);
    sdv[dl*20 + lrow] = (gl < LSEQ) ? softplusf(pdv) : 0.f;
    sbn[dl*20 + lrow] = pbn;
    sgm[dl*20 + lrow] = siluf(zv);
    __syncthreads();
    // ---- phase 3: scan (per lane: channel d0+grp, state n) ----
    float dv[16], xv[16], bn[16];
    #pragma unroll
    for (int q = 0; q < 4; q++) {
      *(floatx4*)(dv + q*4) = *(const floatx4*)(sdv + grp*20 + q*4);
      *(floatx4*)(xv + q*4) = *(const floatx4*)(sxc + grp*20 + q*4);
      *(floatx4*)(bn + q*4) = *(const floatx4*)(sbn + n*20   + q*4);
    }
    float gm = sgm[grp*20 + n];
    float yreg = 0.f, xvn = 0.f;
    #pragma unroll
    for (int j = 0; j < 16; j++) {
      s = __expf(dv[j] * a) * s + (dv[j] * xv[j]) * bn[j];
      float part = s * bn[j];
      part = dpp_addf<0xB1>(part);    // xor 1
      part = dpp_addf<0x4E>(part);    // xor 2
      part = dpp_addf<0x141>(part);   // xor 7 (row_half_mirror)
      part = dpp_addf<0x140>(part);   // xor 15 (row_mirror)
      yreg = (n == j) ? part : yreg;
      xvn  = (n == j) ? xv[j] : xvn;
    }
    int lo = l0 + n;
    if (lo < LSEQ)
      y[(browf + lo) * D_INNER + d0 + grp] = (__bf16)((yreg + dp * xvn) * gm);
    __syncthreads();  // protect LDS reuse by next chunk's phase 2
  }
}

extern "C" void kernel_launch(void* const* d_in, const int* in_sizes, int n_in,
                              void* d_out, int out_size, void* d_ws, size_t ws_size,
                              hipStream_t stream) {
  const float* x         = (const float*)d_in[0];
  const float* conv_w    = (const float*)d_in[1];
  const float* conv_b    = (const float*)d_in[2];
  const float* cls_token = (const float*)d_in[3];
  const float* pos_embed = (const float*)d_in[4];
  const float* ln_w      = (const float*)d_in[5];
  const float* ln_b      = (const float*)d_in[6];
  const float* in_proj_w = (const float*)d_in[7];
  const float* conv1d_w  = (const float*)d_in[8];
  const float* conv1d_b  = (const float*)d_in[9];
  const float* x_proj_w  = (const float*)d_in[10];
  const float* dt_proj_w = (const float*)d_in[11];
  const float* dt_proj_b = (const float*)d_in[12];
  const float* A_log     = (const float*)d_in[13];
  const float* D_param   = (const float*)d_in[14];
  const float* out_proj_w= (const float*)d_in[15];
  const float* norm_w    = (const float*)d_in[16];
  const float* norm_b    = (const float*)d_in[17];

  const int N_IN  = 2*D_INNER*D_MODEL;   // 2359296
  const int N_OUT = D_MODEL*D_INNER;     // 1179648

  char* wsb = (char*)d_ws;
  size_t off = 0;
  float* t     = (float*)(wsb + off); off += (size_t)ROWS*768*4;
  float* xz    = (float*)(wsb + off); off += (size_t)ROWS*3072*4;
  float* part  = (float*)(wsb + off); off += (size_t)2*ROWS*NDTX*4;  // dt(2x1664)/out(4x768) partials
  __bf16* xn_b = (__bf16*)(wsb + off); off += (size_t)MPAD*768*2;
  __bf16* xc_b = (__bf16*)(wsb + off); off += (size_t)MPAD*1536*2;
  __bf16* y_b  = (__bf16*)(wsb + off); off += (size_t)MPAD*1536*2;
  __bf16* col_b= (__bf16*)(wsb + off); off += (size_t)MPAD*768*2;
  __bf16* cw_b = (__bf16*)(wsb + off); off += (size_t)768*768*2;
  __bf16* wb_in  = (__bf16*)(wsb + off); off += (size_t)DEPTH*N_IN*2;
  __bf16* wb_dtx = (__bf16*)(wsb + off); off += (size_t)DEPTH*NDTX*1536*2;
  __bf16* wb_out = (__bf16*)(wsb + off); off += (size_t)DEPTH*N_OUT*2;

  // ---- upfront: all weight conversions ----
  cvt_k<<<(768*768/4 + 255)/256, 256, 0, stream>>>(conv_w, cw_b, 768*768);
  cvt_k<<<(DEPTH*N_IN/4 + 255)/256, 256, 0, stream>>>(in_proj_w, wb_in, DEPTH*N_IN);
  cvt_dtx_k<<<(DEPTH*1552*1536/4 + 255)/256, 256, 0, stream>>>(dt_proj_w, x_proj_w, wb_dtx);
  cvt_k<<<(DEPTH*N_OUT/4 + 255)/256, 256, 0, stream>>>(out_proj_w, wb_out, DEPTH*N_OUT);

  // ---- patch embed as bf16 MFMA GEMM ----
  float* P = xz;  // reuse
  im2col_k<<<(PROWS*768 + 255)/256, 256, 0, stream>>>(x, col_b);
  mgemm3_k<<<25*6, 256, 0, stream>>>(col_b, cw_b, P, 0, PROWS, 768, 768, 768, 6, 6, 0);
  // fused assemble + layer-0 LN
  assemble_ln_k<<<ROWS, 256, 0, stream>>>(P, conv_b, cls_token, pos_embed,
                                          ln_w, ln_b, t, xn_b);

  for (int i = 0; i < DEPTH; i++) {
    // in_proj: N=3072 (nt=24), no split-K -> combos 24, combo-major
    mgemm3_k<<<25*24, 256, 0, stream>>>(xn_b, wb_in + (size_t)i*N_IN, xz, 0,
                                        ROWS, 3072, 768, 768, 24, 24, 0);
    convf_k<<<dim3(8, 6, 8), 256, 0, stream>>>(xz, conv1d_w + (size_t)i*D_INNER*4,
        conv1d_b + (size_t)i*D_INNER, xc_b);
    // dt_proj + folded x_proj(B): N=NDTX (nt=13), split-K x2 -> combos 26, combo-major
    mgemm3_k<<<25*26, 256, 0, stream>>>(xc_b, wb_dtx + (size_t)i*NDTX*1536, part,
        (size_t)ROWS*NDTX, ROWS, NDTX, 1536, 768, 26, 13, 0);
    // fused reduce+transpose+conv+gates+scan
    scan4_k<<<(BATCH*D_INNER)/16, 256, 0, stream>>>(part, xz,
        dt_proj_b + (size_t)i*D_INNER, conv1d_w + (size_t)i*D_INNER*4,
        conv1d_b + (size_t)i*D_INNER, A_log + (size_t)i*D_INNER*D_STATE,
        D_param + (size_t)i*D_INNER, y_b);
    // out_proj: N=768 (nt=6), split-K x4 -> combos 24; m-major XCD chunks
    // (A=y_b 4.8MB >> B 2.4MB); plain partial stores.
    mgemm3_k<<<25*24, 256, 0, stream>>>(y_b, wb_out + (size_t)i*N_OUT, part,
        (size_t)ROWS*768, ROWS, 768, 1536, 384, 24, 6, 1);
    // fused: t += sum(partials); LN -> next xn_b (or final LN -> d_out)
    if (i < DEPTH-1)
      lnf_k<__bf16,1><<<ROWS, 256, 0, stream>>>(t, part,
          ln_w + (size_t)(i+1)*768, ln_b + (size_t)(i+1)*768, xn_b);
    else
      lnf_k<float,2><<<ROWS, 256, 0, stream>>>(t, part, norm_w, norm_b, (float*)d_out);
  }
}

// Round 7
// 1544.534 us; speedup vs baseline: 1.1033x; 1.0494x over previous
//
#include <hip/hip_runtime.h>
#include <math.h>

#define D_MODEL 768
#define D_INNER 1536
#define D_STATE 16
#define DEPTH   12
#define LSEQ    197
#define BATCH   8
#define NPATCH  196
#define ROWS    (BATCH*LSEQ)    // 1576
#define PROWS   (BATCH*NPATCH)  // 1568
#define MPAD    1664            // 26*64, padded row count for bf16 A operands
#define LP      208             // padded time axis (13*16)
#define NDTX    1664            // dt GEMM N: 1536 dt cols + 16 x_proj(B) cols + 112 pad

typedef __bf16 bf16x8 __attribute__((ext_vector_type(8)));
typedef float  floatx4 __attribute__((ext_vector_type(4)));
typedef __attribute__((address_space(1))) void gvoid;
typedef __attribute__((address_space(3))) void svoid;

__device__ __forceinline__ float siluf(float x) { return x / (1.f + __expf(-x)); }
__device__ __forceinline__ float softplusf(float v) {
  return (v > 20.f) ? v : log1pf(__expf(v));
}

__device__ __forceinline__ void gload_lds16(const void* g, void* s) {
  __builtin_amdgcn_global_load_lds((const gvoid*)g, (svoid*)s, 16, 0, 0);
}

// DPP cross-lane add within 16-lane rows (VALU pipe, no DS).
template<int CTRL>
__device__ __forceinline__ float dpp_addf(float x) {
  union { float f; int i; } a, b;
  a.f = x;
  b.i = __builtin_amdgcn_update_dpp(0, a.i, CTRL, 0xF, 0xF, true);
  return x + b.f;
}

// ---------------- fp32 -> bf16 conversion (vectorized, n % 4 == 0) ----------------
__global__ void cvt_k(const float* __restrict__ src, __bf16* __restrict__ dst, int n) {
  int i = (blockIdx.x * 256 + threadIdx.x) * 4;
  if (i >= n) return;
  float4 v = *(const float4*)(src + i);
  union { __bf16 h[4]; unsigned long long u; } p;
  p.h[0] = (__bf16)v.x; p.h[1] = (__bf16)v.y; p.h[2] = (__bf16)v.z; p.h[3] = (__bf16)v.w;
  *(unsigned long long*)(dst + i) = p.u;
}

// ---- combined dt_proj + x_proj(B rows) weight -> bf16 [DEPTH][NDTX][1536] ----
__global__ void cvt_dtx_k(const float* __restrict__ dtw, const float* __restrict__ xpw,
                          __bf16* __restrict__ dst) {
  size_t i = ((size_t)blockIdx.x * 256 + threadIdx.x) * 4;
  const size_t TOT = (size_t)DEPTH * 1552 * 1536;
  if (i >= TOT) return;
  int layer = (int)(i / (1552 * 1536));
  int rem = (int)(i - (size_t)layer * (1552 * 1536));
  int r = rem / 1536, c = rem - r * 1536;
  const float* src = (r < 1536)
      ? dtw + ((size_t)layer * 1536 + r) * 1536 + c
      : xpw + ((size_t)layer * 32 + 16 + (r - 1536)) * 1536 + c;
  float4 v = *(const float4*)src;
  union { __bf16 h[4]; unsigned long long u; } p;
  p.h[0] = (__bf16)v.x; p.h[1] = (__bf16)v.y; p.h[2] = (__bf16)v.z; p.h[3] = (__bf16)v.w;
  *(unsigned long long*)(dst + ((size_t)layer * NDTX + r) * 1536 + c) = p.u;
}

// ---------------- im2col for patch embed (bf16 out) ----------------
__global__ void im2col_k(const float* __restrict__ x, __bf16* __restrict__ col) {
  int idx = blockIdx.x * 256 + threadIdx.x;
  if (idx >= PROWS * 768) return;
  int row = idx / 768, i = idx % 768;
  int b = row / NPATCH, p = row % NPATCH;
  int py = p / 14, px = p % 14;
  int ci = i >> 8, rem = i & 255;
  int ky = rem >> 4, kx = rem & 15;
  col[idx] = (__bf16)x[(((size_t)b*3 + ci)*224 + (py*16+ky))*224 + (px*16+kx)];
}

// ---- fused assemble (cls + patches + pos) -> t, plus layer-0 LN -> xn_b ----
__global__ void assemble_ln_k(const float* __restrict__ P, const float* __restrict__ cb,
                              const float* __restrict__ cls, const float* __restrict__ pos,
                              const float* __restrict__ w, const float* __restrict__ bb,
                              float* __restrict__ t, __bf16* __restrict__ o) {
  int bl = blockIdx.x; int b = bl / LSEQ, l = bl % LSEQ;
  float v[3]; float s = 0.f, ss = 0.f;
  #pragma unroll
  for (int i = 0; i < 3; i++) {
    int c = threadIdx.x + i*256;
    float x;
    if (l == 0) x = cls[c];
    else        x = P[((size_t)b*NPATCH + (l-1))*768 + c] + cb[c];
    x += pos[(size_t)l*768 + c];
    t[(size_t)bl*768 + c] = x;
    v[i] = x; s += x; ss += x*x;
  }
  __shared__ float red[8];
  #pragma unroll
  for (int off = 32; off; off >>= 1) {
    s  += __shfl_down(s, off, 64);
    ss += __shfl_down(ss, off, 64);
  }
  int wv = threadIdx.x >> 6;
  if ((threadIdx.x & 63) == 0) { red[wv] = s; red[wv+4] = ss; }
  __syncthreads();
  if (threadIdx.x == 0) {
    float S = red[0]+red[1]+red[2]+red[3];
    float SS = red[4]+red[5]+red[6]+red[7];
    float m = S * (1.f/768.f);
    float var = SS * (1.f/768.f) - m*m;
    red[0] = m; red[1] = rsqrtf(var + 1e-5f);
  }
  __syncthreads();
  float m = red[0], r = red[1];
  #pragma unroll
  for (int i = 0; i < 3; i++) {
    int c = threadIdx.x + i*256;
    o[(size_t)bl*768 + c] = (__bf16)((v[i]-m)*r*w[c] + bb[c]);
  }
}

// ---------------- layernorm over 768 with optional fused split-K residual ----
// FUSE: 0 = plain LN(t); 1 = t += sum(4 partials), store t, LN; 2 = same but
// don't store t (final layer).
template<typename T, int FUSE>
__global__ void lnf_k(float* __restrict__ t, const float* __restrict__ part,
                      const float* __restrict__ w, const float* __restrict__ b,
                      T* __restrict__ o) {
  int row = blockIdx.x;
  float* tr = t + (size_t)row * 768;
  float v[3]; float s = 0.f, ss = 0.f;
  #pragma unroll
  for (int i = 0; i < 3; i++) {
    int c = threadIdx.x + i*256;
    float x = tr[c];
    if (FUSE) {
      const size_t S = (size_t)ROWS*768, idx = (size_t)row*768 + c;
      x += part[idx] + part[S+idx] + part[2*S+idx] + part[3*S+idx];
      if (FUSE == 1) tr[c] = x;
    }
    v[i] = x; s += x; ss += x*x;
  }
  __shared__ float red[8];
  #pragma unroll
  for (int off = 32; off; off >>= 1) {
    s  += __shfl_down(s, off, 64);
    ss += __shfl_down(ss, off, 64);
  }
  int wv = threadIdx.x >> 6;
  if ((threadIdx.x & 63) == 0) { red[wv] = s; red[wv+4] = ss; }
  __syncthreads();
  if (threadIdx.x == 0) {
    float S = red[0]+red[1]+red[2]+red[3];
    float SS = red[4]+red[5]+red[6]+red[7];
    float m = S * (1.f/768.f);
    float var = SS * (1.f/768.f) - m*m;
    red[0] = m; red[1] = rsqrtf(var + 1e-5f);
  }
  __syncthreads();
  float m = red[0], r = red[1];
  #pragma unroll
  for (int i = 0; i < 3; i++) {
    int c = threadIdx.x + i*256;
    o[(size_t)row*768 + c] = (T)((v[i]-m)*r*w[c] + b[c]);
  }
}

// ---------------- bf16 MFMA GEMM v3: TM=64, TN=128, BK=64, 2D XCD chunks ----
// v-enumeration: v = (cblk*25 + mt)*G + cw, c = cblk*G + cw. The bijective
// 8-chunk slicing of v-space then gives each XCD a rectangle of
// {1 combo-subgroup of size G} x {a contiguous m-range}, sized so each XCD's
// A-slice + B-slice fits its private 4MB L2 (in_proj G=6: 2.5MB; dt G=13 =
// one z-split: 3.2MB; out G=12: 1.8MB). Avoids streaming the full A (or B)
// panel through every XCD (old 1D chunking: dt A=4.8MB > L2, 8x re-stream).
__global__ __launch_bounds__(256) void mgemm3_k(const __bf16* __restrict__ A,
    const __bf16* __restrict__ W, float* __restrict__ C, size_t pstride,
    int M, int N, int K, int Ksub, int combos, int nt, int G) {
  __shared__ __bf16 sA[2][64*64];
  __shared__ __bf16 sB[2][128*64];
  const int lin = blockIdx.x;
  const int nwg = combos * 25;
  const int q = nwg >> 3, r = nwg & 7;
  const int xcd = lin & 7, idx = lin >> 3;
  const int v = (xcd < r ? xcd * (q + 1) : r * (q + 1) + (xcd - r) * q) + idx;
  const int mgsz = 25 * G;
  const int cblk = v / mgsz; const int rem = v - cblk * mgsz;
  const int mt = rem / G;   const int cw = rem - mt * G;
  const int c = cblk * G + cw;
  const int ntile = c % nt, z = c / nt;
  const int m0 = mt * 64, n0 = ntile * 128;
  const int kbeg = z * Ksub, kend = kbeg + Ksub;

  const int tid = threadIdx.x, wave = tid >> 6, lane = tid & 63;
  const int wm = (wave & 1) * 32, wn = (wave >> 1) * 64;

  floatx4 acc[2][4] = {};

  const int srow = tid >> 3;
  const int scol = ((tid & 7) ^ (srow & 7)) * 8;
  const __bf16* gA = A + (size_t)(m0 + srow) * K + scol;
  const __bf16* gB = W + (size_t)(n0 + srow) * K + scol;

  const int lm = lane & 15, lk = lane >> 4;
  const int g0 = ((lk    ) ^ (lane & 7)) * 8;
  const int g1 = ((lk + 4) ^ (lane & 7)) * 8;

  int buf = 0;
  {
    #pragma unroll
    for (int p = 0; p < 2; p++)
      gload_lds16(gA + (size_t)(p*32)*K + kbeg, sA[0] + p*2048 + tid*8);
    #pragma unroll
    for (int p = 0; p < 4; p++)
      gload_lds16(gB + (size_t)(p*32)*K + kbeg, sB[0] + p*2048 + tid*8);
  }

  for (int k0 = kbeg; k0 < kend; k0 += 64) {
    __syncthreads();
    if (k0 + 64 < kend) {
      const int nb = buf ^ 1;
      #pragma unroll
      for (int p = 0; p < 2; p++)
        gload_lds16(gA + (size_t)(p*32)*K + (k0+64), sA[nb] + p*2048 + tid*8);
      #pragma unroll
      for (int p = 0; p < 4; p++)
        gload_lds16(gB + (size_t)(p*32)*K + (k0+64), sB[nb] + p*2048 + tid*8);
    }
    const __bf16* pA = sA[buf] + (wm + lm) * 64;
    const __bf16* pB = sB[buf] + (wn + lm) * 64;
    bf16x8 a0[2], a1[2], b0[4], b1[4];
    #pragma unroll
    for (int i = 0; i < 2; i++) {
      a0[i] = *(const bf16x8*)(pA + i*1024 + g0);
      a1[i] = *(const bf16x8*)(pA + i*1024 + g1);
    }
    #pragma unroll
    for (int j = 0; j < 4; j++) {
      b0[j] = *(const bf16x8*)(pB + j*1024 + g0);
      b1[j] = *(const bf16x8*)(pB + j*1024 + g1);
    }
    #pragma unroll
    for (int i = 0; i < 2; i++)
      #pragma unroll
      for (int j = 0; j < 4; j++) {
        acc[i][j] = __builtin_amdgcn_mfma_f32_16x16x32_bf16(a0[i], b0[j], acc[i][j], 0, 0, 0);
        acc[i][j] = __builtin_amdgcn_mfma_f32_16x16x32_bf16(a1[i], b1[j], acc[i][j], 0, 0, 0);
      }
    buf ^= 1;
  }

  float* Cp = C + (size_t)z * pstride;
  const int en = n0 + wn + lm;
  const int em = m0 + wm + lk * 4;
  #pragma unroll
  for (int i = 0; i < 2; i++) {
    #pragma unroll
    for (int r2 = 0; r2 < 4; r2++) {
      int m = em + i * 16 + r2;
      if (m >= M) continue;
      #pragma unroll
      for (int j = 0; j < 4; j++)
        Cp[(size_t)m * N + en + j * 16] = acc[i][j][r2];
    }
  }
}

// ---------------- depthwise conv1d + silu -> bf16 GEMM-A operand -----------
__global__ __launch_bounds__(256) void convf_k(const float* __restrict__ xz,
    const float* __restrict__ cw, const float* __restrict__ cb,
    __bf16* __restrict__ xc_b) {
  const int b = blockIdx.x, dc = blockIdx.y, lc = blockIdx.z * 28;
  const int d = dc * 256 + threadIdx.x;
  const int lend = min(lc + 28, LSEQ);
  const float* w = cw + (size_t)d * 4;
  const float w0 = w[0], w1 = w[1], w2 = w[2], w3 = w[3];
  const float bias = cb[d];
  float xm3 = 0.f, xm2 = 0.f, xm1 = 0.f;
  const size_t rowbase = ((size_t)b * LSEQ) * 3072 + d;
  if (lc >= 3) {
    xm3 = xz[rowbase + (size_t)(lc-3)*3072];
    xm2 = xz[rowbase + (size_t)(lc-2)*3072];
    xm1 = xz[rowbase + (size_t)(lc-1)*3072];
  }
  for (int l = lc; l < lend; l++) {
    float x0 = xz[rowbase + (size_t)l*3072];
    float cv = w0*xm3 + w1*xm2 + w2*xm1 + w3*x0 + bias;
    xm3 = xm2; xm2 = xm1; xm1 = x0;
    xc_b[((size_t)b*LSEQ + l)*D_INNER + d] = (__bf16)siluf(cv);
  }
}

// ---------------- fused reduce+transpose+gates+selective scan ----------------
// One block = 16 consecutive channels (d0..d0+15) of one batch b, all 197 steps.
// Per 16-step chunk, 256 threads stage 16l x 16d tiles: softplus(dt) from the
// dt split-K partials (bias fused), B from the folded x_proj columns, the gate
// silu(z) from xz, and xv directly from xc_b (the same bf16 silu(conv) the dt
// GEMM consumed — no conv recompute, no halo, one fewer barrier). Tail
// l>=LSEQ steps are exact identities (dv=0 -> s unchanged).
__global__ __launch_bounds__(256) void scan4_k(const float* __restrict__ p0,
    const float* __restrict__ xz, const __bf16* __restrict__ xc,
    const float* __restrict__ dt_bias, const float* __restrict__ A_log,
    const float* __restrict__ Dp, __bf16* __restrict__ y) {
  __shared__ __align__(16) float sdv[16*20];  // softplus(dt) [dl][l], pad 20
  __shared__ __align__(16) float sbn[16*20];  // B [n][l]
  __shared__ __align__(16) float sxc[16*20];  // silu(conv(x)) [dl][l]
  __shared__ __align__(16) float sgm[16*20];  // silu(z) [dl][l]

  const float* p1 = p0 + (size_t)ROWS * NDTX;
  const int t = threadIdx.x;
  const int b = blockIdx.x / 96;           // 96 blocks per batch (1536/16)
  const int d0 = (blockIdx.x - b * 96) * 16;
  const int lrow = t >> 4, dl = t & 15;    // staging role
  const int grp = t >> 4, n = t & 15;      // compute role (same decomposition)

  const float spbias = dt_bias[d0 + dl];
  const float a  = -__expf(A_log[(size_t)(d0 + grp) * 16 + n]);
  const float dp = Dp[d0 + grp];

  const size_t browf = (size_t)b * LSEQ;
  float s = 0.f;

  for (int l0 = 0; l0 < LP; l0 += 16) {
    // ---- phase 1: global loads + derived tiles ----
    int gl = l0 + lrow;
    float pdv = 0.f, pbn = 0.f, zv = 0.f, xcv = 0.f;
    if (gl < LSEQ) {
      size_t row = browf + gl;
      size_t pr = row * NDTX;
      pdv = p0[pr + d0 + dl] + p1[pr + d0 + dl] + spbias;
      pbn = p0[pr + 1536 + dl] + p1[pr + 1536 + dl];
      zv  = xz[row * 3072 + 1536 + d0 + dl];
      xcv = (float)xc[row * D_INNER + d0 + dl];
    }
    sxc[dl*20 + lrow] = xcv;
    sdv[dl*20 + lrow] = (gl < LSEQ) ? softplusf(pdv) : 0.f;
    sbn[dl*20 + lrow] = pbn;
    sgm[dl*20 + lrow] = siluf(zv);
    __syncthreads();
    // ---- phase 2: scan (per lane: channel d0+grp, state n) ----
    float dv[16], xv[16], bn[16];
    #pragma unroll
    for (int q = 0; q < 4; q++) {
      *(floatx4*)(dv + q*4) = *(const floatx4*)(sdv + grp*20 + q*4);
      *(floatx4*)(xv + q*4) = *(const floatx4*)(sxc + grp*20 + q*4);
      *(floatx4*)(bn + q*4) = *(const floatx4*)(sbn + n*20   + q*4);
    }
    float gm = sgm[grp*20 + n];
    float yreg = 0.f, xvn = 0.f;
    #pragma unroll
    for (int j = 0; j < 16; j++) {
      s = __expf(dv[j] * a) * s + (dv[j] * xv[j]) * bn[j];
      float part = s * bn[j];
      part = dpp_addf<0xB1>(part);    // xor 1
      part = dpp_addf<0x4E>(part);    // xor 2
      part = dpp_addf<0x141>(part);   // xor 7 (row_half_mirror)
      part = dpp_addf<0x140>(part);   // xor 15 (row_mirror)
      yreg = (n == j) ? part : yreg;
      xvn  = (n == j) ? xv[j] : xvn;
    }
    int lo = l0 + n;
    if (lo < LSEQ)
      y[(browf + lo) * D_INNER + d0 + grp] = (__bf16)((yreg + dp * xvn) * gm);
    __syncthreads();  // protect LDS reuse by next chunk's stores
  }
}

extern "C" void kernel_launch(void* const* d_in, const int* in_sizes, int n_in,
                              void* d_out, int out_size, void* d_ws, size_t ws_size,
                              hipStream_t stream) {
  const float* x         = (const float*)d_in[0];
  const float* conv_w    = (const float*)d_in[1];
  const float* conv_b    = (const float*)d_in[2];
  const float* cls_token = (const float*)d_in[3];
  const float* pos_embed = (const float*)d_in[4];
  const float* ln_w      = (const float*)d_in[5];
  const float* ln_b      = (const float*)d_in[6];
  const float* in_proj_w = (const float*)d_in[7];
  const float* conv1d_w  = (const float*)d_in[8];
  const float* conv1d_b  = (const float*)d_in[9];
  const float* x_proj_w  = (const float*)d_in[10];
  const float* dt_proj_w = (const float*)d_in[11];
  const float* dt_proj_b = (const float*)d_in[12];
  const float* A_log     = (const float*)d_in[13];
  const float* D_param   = (const float*)d_in[14];
  const float* out_proj_w= (const float*)d_in[15];
  const float* norm_w    = (const float*)d_in[16];
  const float* norm_b    = (const float*)d_in[17];

  const int N_IN  = 2*D_INNER*D_MODEL;   // 2359296
  const int N_OUT = D_MODEL*D_INNER;     // 1179648

  char* wsb = (char*)d_ws;
  size_t off = 0;
  float* t     = (float*)(wsb + off); off += (size_t)ROWS*768*4;
  float* xz    = (float*)(wsb + off); off += (size_t)ROWS*3072*4;
  float* part  = (float*)(wsb + off); off += (size_t)2*ROWS*NDTX*4;  // dt(2x1664)/out(4x768) partials
  __bf16* xn_b = (__bf16*)(wsb + off); off += (size_t)MPAD*768*2;
  __bf16* xc_b = (__bf16*)(wsb + off); off += (size_t)MPAD*1536*2;
  __bf16* y_b  = (__bf16*)(wsb + off); off += (size_t)MPAD*1536*2;
  __bf16* col_b= (__bf16*)(wsb + off); off += (size_t)MPAD*768*2;
  __bf16* cw_b = (__bf16*)(wsb + off); off += (size_t)768*768*2;
  __bf16* wb_in  = (__bf16*)(wsb + off); off += (size_t)DEPTH*N_IN*2;
  __bf16* wb_dtx = (__bf16*)(wsb + off); off += (size_t)DEPTH*NDTX*1536*2;
  __bf16* wb_out = (__bf16*)(wsb + off); off += (size_t)DEPTH*N_OUT*2;

  // ---- upfront: all weight conversions ----
  cvt_k<<<(768*768/4 + 255)/256, 256, 0, stream>>>(conv_w, cw_b, 768*768);
  cvt_k<<<(DEPTH*N_IN/4 + 255)/256, 256, 0, stream>>>(in_proj_w, wb_in, DEPTH*N_IN);
  cvt_dtx_k<<<(DEPTH*1552*1536/4 + 255)/256, 256, 0, stream>>>(dt_proj_w, x_proj_w, wb_dtx);
  cvt_k<<<(DEPTH*N_OUT/4 + 255)/256, 256, 0, stream>>>(out_proj_w, wb_out, DEPTH*N_OUT);

  // ---- patch embed as bf16 MFMA GEMM ----
  float* P = xz;  // reuse
  im2col_k<<<(PROWS*768 + 255)/256, 256, 0, stream>>>(x, col_b);
  mgemm3_k<<<25*6, 256, 0, stream>>>(col_b, cw_b, P, 0, PROWS, 768, 768, 768, 6, 6, 6);
  // fused assemble + layer-0 LN
  assemble_ln_k<<<ROWS, 256, 0, stream>>>(P, conv_b, cls_token, pos_embed,
                                          ln_w, ln_b, t, xn_b);

  for (int i = 0; i < DEPTH; i++) {
    // in_proj: N=3072 (nt=24), no split-K -> combos 24; 2x4 XCD rectangles (G=6)
    mgemm3_k<<<25*24, 256, 0, stream>>>(xn_b, wb_in + (size_t)i*N_IN, xz, 0,
                                        ROWS, 3072, 768, 768, 24, 24, 6);
    convf_k<<<dim3(8, 6, 8), 256, 0, stream>>>(xz, conv1d_w + (size_t)i*D_INNER*4,
        conv1d_b + (size_t)i*D_INNER, xc_b);
    // dt_proj + folded x_proj(B): N=NDTX (nt=13), split-K x2 -> combos 26;
    // G=13 -> each XCD: one z-split x ~6 m-tiles x all n (3.2MB, L2-fits)
    mgemm3_k<<<25*26, 256, 0, stream>>>(xc_b, wb_dtx + (size_t)i*NDTX*1536, part,
        (size_t)ROWS*NDTX, ROWS, NDTX, 1536, 768, 26, 13, 13);
    // fused reduce+transpose+gates+scan (xv straight from xc_b)
    scan4_k<<<(BATCH*D_INNER)/16, 256, 0, stream>>>(part, xz, xc_b,
        dt_proj_b + (size_t)i*D_INNER, A_log + (size_t)i*D_INNER*D_STATE,
        D_param + (size_t)i*D_INNER, y_b);
    // out_proj: N=768 (nt=6), split-K x4 -> combos 24; G=12 -> 2x4 rectangles
    mgemm3_k<<<25*24, 256, 0, stream>>>(y_b, wb_out + (size_t)i*N_OUT, part,
        (size_t)ROWS*768, ROWS, 768, 1536, 384, 24, 6, 12);
    // fused: t += sum(partials); LN -> next xn_b (or final LN -> d_out)
    if (i < DEPTH-1)
      lnf_k<__bf16,1><<<ROWS, 256, 0, stream>>>(t, part,
          ln_w + (size_t)(i+1)*768, ln_b + (size_t)(i+1)*768, xn_b);
    else
      lnf_k<float,2><<<ROWS, 256, 0, stream>>>(t, part, norm_w, norm_b, (float*)d_out);
  }
}